// Round 7
// baseline (440.596 us; speedup 1.0000x reference)
//
#include <hip/hip_runtime.h>
#include <hip/hip_bf16.h>
#include <math.h>

#define B_N 16384
#define D_K 256
#define JS 8
#define JRANGE (B_N / JS)          // 2048 j-rows per block
#define TJ 32                      // j-rows per LDS tile
#define NT (JRANGE / TJ)           // 64 tiles
#define TILE_BYTES (TJ * D_K * 2)  // 16 KB

typedef __bf16 bf16x8 __attribute__((ext_vector_type(8)));
typedef float f32x16 __attribute__((ext_vector_type(16)));

__device__ __forceinline__ unsigned short f2bf(float x) {
  unsigned u = __float_as_uint(x);
  unsigned r = (u + 0x7fffu + ((u >> 16) & 1u)) >> 16;
  return (unsigned short)r;
}

__device__ __forceinline__ float fexp2(float x) {
#if __has_builtin(__builtin_amdgcn_exp2f)
  return __builtin_amdgcn_exp2f(x);
#else
  return exp2f(x);
#endif
}

__device__ __forceinline__ void load_lds16(const void* g, void* l) {
  __builtin_amdgcn_global_load_lds(
      (const __attribute__((address_space(1))) unsigned int*)g,
      (__attribute__((address_space(3))) unsigned int*)l, 16, 0, 0);
}

// ---------------------------------------------------------------------------
// 1) fp32 -> bf16 (z_seal pre-scaled by scale*log2e) + diag fused.
// ---------------------------------------------------------------------------
__global__ void convert_diag_kernel(const float* __restrict__ A, const float* __restrict__ Bm,
                                    const float* __restrict__ lsp,
                                    unsigned short* __restrict__ Abf,
                                    unsigned short* __restrict__ Bbf,
                                    float* __restrict__ diag) {
  const float c = fminf(expf(lsp[0]), 100.0f) * 1.4426950408889634f;
  const int tid = threadIdx.x;
  const int idx = (blockIdx.x * 256 + tid) * 4;
  float4 a = *(const float4*)(A + idx);
  float4 b = *(const float4*)(Bm + idx);
  ushort4 ua, ub;
  ua.x = f2bf(a.x); ua.y = f2bf(a.y); ua.z = f2bf(a.z); ua.w = f2bf(a.w);
  ub.x = f2bf(b.x * c); ub.y = f2bf(b.y * c); ub.z = f2bf(b.z * c); ub.w = f2bf(b.w * c);
  *(ushort4*)(Abf + idx) = ua;
  *(ushort4*)(Bbf + idx) = ub;
  float d = a.x * b.x + a.y * b.y + a.z * b.z + a.w * b.w;
#pragma unroll
  for (int off = 32; off; off >>= 1) d += __shfl_xor(d, off);
  if ((tid & 63) == 0) diag[blockIdx.x * 4 + (tid >> 6)] = d;
}

// ---------------------------------------------------------------------------
// 2) Fused GEMM + online logsumexp.
//    R7: R5 structure (64 i-rows/wave, xf reg-resident, 2 waves/SIMD) +
//    double acc phase (accA/accB): tile t's MFMA burst overlaps tile t-1's
//    softmax update (independent -> wave fills MFMA dependency gaps with
//    VALU/trans work instead of stalling).
//    R4 lesson: X fragments MUST stay register-resident; need ~235 regs <
//    256 cap at (256,2). Remat signature = FETCH_SIZE explosion.
// ---------------------------------------------------------------------------
__device__ __forceinline__ void upd(float& m, float& s, f32x16& a) {
  float x0 = fmaxf(fmaxf(a[0], a[1]), a[2]);
  float x1 = fmaxf(fmaxf(a[3], a[4]), a[5]);
  float x2 = fmaxf(fmaxf(a[6], a[7]), a[8]);
  float x3 = fmaxf(fmaxf(a[9], a[10]), a[11]);
  float x4 = fmaxf(fmaxf(a[12], a[13]), a[14]);
  float y0 = fmaxf(fmaxf(x0, x1), x2);
  float y1 = fmaxf(fmaxf(x3, x4), a[15]);
  float mn = fmaxf(m, fmaxf(y0, y1));
  s *= fexp2(m - mn);
  float p0 = fexp2(a[0] - mn), p1 = fexp2(a[1] - mn);
  float p2 = fexp2(a[2] - mn), p3 = fexp2(a[3] - mn);
  p0 += fexp2(a[4] - mn);  p1 += fexp2(a[5] - mn);
  p2 += fexp2(a[6] - mn);  p3 += fexp2(a[7] - mn);
  p0 += fexp2(a[8] - mn);  p1 += fexp2(a[9] - mn);
  p2 += fexp2(a[10] - mn); p3 += fexp2(a[11] - mn);
  p0 += fexp2(a[12] - mn); p1 += fexp2(a[13] - mn);
  p2 += fexp2(a[14] - mn); p3 += fexp2(a[15] - mn);
  s += (p0 + p1) + (p2 + p3);
  m = mn;
  a = (f32x16){};  // re-zero for reuse as next MFMA C-input
}

__global__ __launch_bounds__(256, 2) void lse_kernel(const unsigned short* __restrict__ Abf,
                                                     const unsigned short* __restrict__ Bbf,
                                                     float* __restrict__ pm,
                                                     float* __restrict__ ps) {
  __shared__ __align__(16) unsigned char lds[2][TILE_BYTES];
  const int bid = blockIdx.x;
  const int dir = bid >> 9;            // 0/1
  const int iblk = (bid >> 3) & 63;    // 64 i-blocks of 256 rows
  const int js = bid & 7;              // low bits -> same js pinned per XCD
  const unsigned short* X = dir ? Bbf : Abf;
  const unsigned short* Y = dir ? Abf : Bbf;
  const int i0 = iblk * 256;
  const int j0 = js * JRANGE;
  const int w = threadIdx.x >> 6;
  const int l = threadIdx.x & 63;
  const int lc = l & 31, lh = l >> 5;

  // X fragments: this wave's 64 rows x 256 k (128 VGPR, register-resident)
  bf16x8 xf0[16], xf1[16];
  {
    const unsigned short* Xr0 = X + (size_t)(i0 + w * 64 + lc) * D_K + lh * 8;
#pragma unroll
    for (int kk = 0; kk < 16; ++kk) {
      xf0[kk] = *(const bf16x8*)(Xr0 + kk * 16);
      xf1[kk] = *(const bf16x8*)(Xr0 + 32 * D_K + kk * 16);
    }
  }

  float m0 = -INFINITY, s0 = 0.f, m1 = -INFINITY, s1 = 0.f;
  f32x16 accA0 = {}, accA1 = {}, accB0 = {}, accB1 = {};

  // Running per-lane swizzled source pointers (advance 1 tile per STAGE).
  const unsigned short* srcs[4];
  unsigned dsts[4];
#pragma unroll
  for (int r = 0; r < 4; ++r) {
    const int row = w * 8 + 2 * r + lh;
    srcs[r] = Y + (size_t)(j0 + row) * D_K + ((lc ^ (row & 7)) << 3);
    dsts[r] = w * 4096 + r * 1024;
  }

#define STAGE(bufidx)                                  \
  {                                                    \
    _Pragma("unroll") for (int r = 0; r < 4; ++r) {    \
      load_lds16(srcs[r], &lds[bufidx][dsts[r]]);      \
      srcs[r] += TJ * D_K;                             \
    }                                                  \
  }

  // ds_read address: lc*512 + (((2kk+lh)^(lc&7))<<4) == vb ^ (kk<<5)
  const unsigned vb = (unsigned)lc * 512 + ((unsigned)(lh ^ (lc & 7)) << 4);

  // Half-burst: 8 kk-steps x 2 subs = 16 MFMA from lds[bufidx]
#define HALF(bufidx, c0, c1, kklo)                                              \
  {                                                                            \
    const unsigned char* lb = &lds[bufidx][0];                                 \
    _Pragma("unroll") for (int kk = (kklo); kk < (kklo) + 8; ++kk) {           \
      bf16x8 y = *(const bf16x8*)(lb + (vb ^ (unsigned)(kk << 5)));            \
      c0 = __builtin_amdgcn_mfma_f32_32x32x16_bf16(y, xf0[kk], c0, 0, 0, 0);   \
      c1 = __builtin_amdgcn_mfma_f32_32x32x16_bf16(y, xf1[kk], c1, 0, 0, 0);   \
    }                                                                          \
  }

  // Pipelined consume: MFMA tile->cur interleaved with softmax of prev tile.
#define CPIPE(bufidx, c0, c1, p0, p1) \
  HALF(bufidx, c0, c1, 0);            \
  upd(m0, s0, p0);                    \
  HALF(bufidx, c0, c1, 8);            \
  upd(m1, s1, p1);

  // prologue: tile0 -> accA (no upd yet)
  STAGE(0);
  __syncthreads();                   // tile0 in buf0
  STAGE(1);                          // prefetch tile1
  HALF(0, accA0, accA1, 0);
  HALF(0, accA0, accA1, 8);
  __syncthreads();                   // tile1 in buf1; buf0 free

  // tiles 1..62 in pairs; tile t odd in buf1, even in buf0
  for (int t = 1; t < NT - 1; t += 2) {
    STAGE(0);                        // tile t+1 -> buf0 (t+1 <= 62)
    CPIPE(1, accB0, accB1, accA0, accA1);
    __syncthreads();                 // tile t+1 ready; buf1 free
    STAGE(1);                        // tile t+2 -> buf1 (t+2 <= 63)
    CPIPE(0, accA0, accA1, accB0, accB1);
    __syncthreads();                 // tile t+2 ready; buf0 free
  }
  // tile 63 (odd, buf1): fill accB, retire accA
  CPIPE(1, accB0, accB1, accA0, accA1);
  // retire accB
  upd(m0, s0, accB0);
  upd(m1, s1, accB1);
#undef STAGE
#undef HALF
#undef CPIPE

  // combine lane l with l^32 (same i, disjoint j_local subsets)
  {
    float mo = __shfl_xor(m0, 32), so = __shfl_xor(s0, 32);
    float mn = fmaxf(m0, mo);
    s0 = s0 * fexp2(m0 - mn) + so * fexp2(mo - mn); m0 = mn;
    mo = __shfl_xor(m1, 32); so = __shfl_xor(s1, 32);
    mn = fmaxf(m1, mo);
    s1 = s1 * fexp2(m1 - mn) + so * fexp2(mo - mn); m1 = mn;
  }

  // per-wave rows complete over this block's j-range: write partials
  if (lh == 0) {
    const int base = js * (2 * B_N) + dir * B_N + i0 + w * 64 + lc;
    pm[base] = m0;      ps[base] = s0;
    pm[base + 32] = m1; ps[base + 32] = s1;
  }
}

// ---------------------------------------------------------------------------
// 3) combine JS partials per (dir,i) -> lse (natural log)
// ---------------------------------------------------------------------------
__global__ void combine_kernel(const float* __restrict__ pm, const float* __restrict__ ps,
                               float* __restrict__ lse) {
  int id = blockIdx.x * 256 + threadIdx.x;  // dir*B_N + i
  float m = -INFINITY, s = 0.f;
#pragma unroll
  for (int p = 0; p < JS; ++p) {
    float mo = pm[p * (2 * B_N) + id], so = ps[p * (2 * B_N) + id];
    float mn = fmaxf(m, mo);
    s = s * fexp2(m - mn) + so * fexp2(mo - mn);
    m = mn;
  }
  lse[id] = 0.6931471805599453f * (m + log2f(s));
}

// ---------------------------------------------------------------------------
// 4) final: loss = mean( 0.5*(lse_r+lse_c) - scale*diag )
// ---------------------------------------------------------------------------
__global__ void final_kernel(const float* __restrict__ lse, const float* __restrict__ diag,
                             const float* __restrict__ lsp, float* __restrict__ out) {
  const float scale = fminf(expf(lsp[0]), 100.0f);
  float part = 0.f;
  for (int i = threadIdx.x; i < B_N; i += 1024)
    part += 0.5f * (lse[i] + lse[B_N + i]) - scale * diag[i];
  __shared__ float red[1024];
  red[threadIdx.x] = part;
  __syncthreads();
  for (int off = 512; off; off >>= 1) {
    if (threadIdx.x < off) red[threadIdx.x] += red[threadIdx.x + off];
    __syncthreads();
  }
  if (threadIdx.x == 0) {
    float loss = red[0] / (float)B_N;
    out[0] = loss;
    out[1] = loss;
  }
}

extern "C" void kernel_launch(void* const* d_in, const int* in_sizes, int n_in,
                              void* d_out, int out_size, void* d_ws, size_t ws_size,
                              hipStream_t stream) {
  const float* A  = (const float*)d_in[0];  // z_schema
  const float* Bm = (const float*)d_in[1];  // z_seal
  const float* ls = (const float*)d_in[2];  // logit_scale
  float* out = (float*)d_out;

  char* ws = (char*)d_ws;
  unsigned short* Abf = (unsigned short*)ws;                        // 8 MB
  unsigned short* Bbf = Abf + (size_t)B_N * D_K;                    // 8 MB
  float* diagp = (float*)(ws + 2ull * B_N * D_K * 2);               // 64 KB
  float* lsep  = diagp + B_N;                                       // 128 KB
  float* pm    = lsep + 2 * B_N;                                    // 1 MB
  float* ps    = pm + JS * 2 * B_N;                                 // 1 MB

  convert_diag_kernel<<<4096, 256, 0, stream>>>(A, Bm, ls, Abf, Bbf, diagp);
  lse_kernel<<<1024, 256, 0, stream>>>(Abf, Bbf, pm, ps);
  combine_kernel<<<128, 256, 0, stream>>>(pm, ps, lsep);
  final_kernel<<<1, 1024, 0, stream>>>(lsep, diagp, ls, out);
}

// Round 8
// 385.985 us; speedup vs baseline: 1.1415x; 1.1415x over previous
//
#include <hip/hip_runtime.h>
#include <hip/hip_bf16.h>
#include <math.h>

#define B_N 16384
#define D_K 256
#define JS 8
#define JRANGE (B_N / JS)          // 2048 j-rows per block
#define TJ 32                      // j-rows per LDS tile
#define NT (JRANGE / TJ)           // 64 tiles
#define TILE_BYTES (TJ * D_K * 2)  // 16 KB

typedef __bf16 bf16x8 __attribute__((ext_vector_type(8)));
typedef float f32x16 __attribute__((ext_vector_type(16)));

__device__ __forceinline__ unsigned short f2bf(float x) {
  unsigned u = __float_as_uint(x);
  unsigned r = (u + 0x7fffu + ((u >> 16) & 1u)) >> 16;
  return (unsigned short)r;
}

__device__ __forceinline__ float fexp2(float x) {
#if __has_builtin(__builtin_amdgcn_exp2f)
  return __builtin_amdgcn_exp2f(x);
#else
  return exp2f(x);
#endif
}

__device__ __forceinline__ void load_lds16(const void* g, void* l) {
  __builtin_amdgcn_global_load_lds(
      (const __attribute__((address_space(1))) unsigned int*)g,
      (__attribute__((address_space(3))) unsigned int*)l, 16, 0, 0);
}

// ---------------------------------------------------------------------------
// 1) fp32 -> bf16 (z_seal pre-scaled by scale*log2e) + diag fused.
// ---------------------------------------------------------------------------
__global__ void convert_diag_kernel(const float* __restrict__ A, const float* __restrict__ Bm,
                                    const float* __restrict__ lsp,
                                    unsigned short* __restrict__ Abf,
                                    unsigned short* __restrict__ Bbf,
                                    float* __restrict__ diag) {
  const float c = fminf(expf(lsp[0]), 100.0f) * 1.4426950408889634f;
  const int tid = threadIdx.x;
  const int idx = (blockIdx.x * 256 + tid) * 4;
  float4 a = *(const float4*)(A + idx);
  float4 b = *(const float4*)(Bm + idx);
  ushort4 ua, ub;
  ua.x = f2bf(a.x); ua.y = f2bf(a.y); ua.z = f2bf(a.z); ua.w = f2bf(a.w);
  ub.x = f2bf(b.x * c); ub.y = f2bf(b.y * c); ub.z = f2bf(b.z * c); ub.w = f2bf(b.w * c);
  *(ushort4*)(Abf + idx) = ua;
  *(ushort4*)(Bbf + idx) = ub;
  float d = a.x * b.x + a.y * b.y + a.z * b.z + a.w * b.w;
#pragma unroll
  for (int off = 32; off; off >>= 1) d += __shfl_xor(d, off);
  if ((tid & 63) == 0) diag[blockIdx.x * 4 + (tid >> 6)] = d;
}

// ---------------------------------------------------------------------------
// 2) Fused GEMM + online logsumexp.
//    R8: double-acc pipeline (tile t MFMA burst overlaps tile t-1 softmax)
//    at __launch_bounds__(256,1): 1 wave/EU -> up to 512 regs/wave, so
//    xf(128)+accA/accB(64)+misc ~240 fit with NO spill/remat.
//    R4/R7 lesson: if the allocator can't grant xf+acc, codegen remats X
//    from global (FETCH 72MB->335MB) or spills (WRITE 92MB). Tripwire:
//    FETCH_SIZE must stay ~72MB, WRITE_SIZE ~2MB.
// ---------------------------------------------------------------------------
__device__ __forceinline__ void upd(float& m, float& s, f32x16& a) {
  float x0 = fmaxf(fmaxf(a[0], a[1]), a[2]);
  float x1 = fmaxf(fmaxf(a[3], a[4]), a[5]);
  float x2 = fmaxf(fmaxf(a[6], a[7]), a[8]);
  float x3 = fmaxf(fmaxf(a[9], a[10]), a[11]);
  float x4 = fmaxf(fmaxf(a[12], a[13]), a[14]);
  float y0 = fmaxf(fmaxf(x0, x1), x2);
  float y1 = fmaxf(fmaxf(x3, x4), a[15]);
  float mn = fmaxf(m, fmaxf(y0, y1));
  s *= fexp2(m - mn);
  float p0 = fexp2(a[0] - mn), p1 = fexp2(a[1] - mn);
  float p2 = fexp2(a[2] - mn), p3 = fexp2(a[3] - mn);
  p0 += fexp2(a[4] - mn);  p1 += fexp2(a[5] - mn);
  p2 += fexp2(a[6] - mn);  p3 += fexp2(a[7] - mn);
  p0 += fexp2(a[8] - mn);  p1 += fexp2(a[9] - mn);
  p2 += fexp2(a[10] - mn); p3 += fexp2(a[11] - mn);
  p0 += fexp2(a[12] - mn); p1 += fexp2(a[13] - mn);
  p2 += fexp2(a[14] - mn); p3 += fexp2(a[15] - mn);
  s += (p0 + p1) + (p2 + p3);
  m = mn;
  a = (f32x16){};  // re-zero for reuse as next MFMA C-input
}

__global__ __launch_bounds__(256, 1) void lse_kernel(const unsigned short* __restrict__ Abf,
                                                     const unsigned short* __restrict__ Bbf,
                                                     float* __restrict__ pm,
                                                     float* __restrict__ ps) {
  __shared__ __align__(16) unsigned char lds[2][TILE_BYTES];
  const int bid = blockIdx.x;
  const int dir = bid >> 9;            // 0/1
  const int iblk = (bid >> 3) & 63;    // 64 i-blocks of 256 rows
  const int js = bid & 7;              // low bits -> same js pinned per XCD
  const unsigned short* X = dir ? Bbf : Abf;
  const unsigned short* Y = dir ? Abf : Bbf;
  const int i0 = iblk * 256;
  const int j0 = js * JRANGE;
  const int w = threadIdx.x >> 6;
  const int l = threadIdx.x & 63;
  const int lc = l & 31, lh = l >> 5;

  // X fragments: this wave's 64 rows x 256 k (128 VGPR, register-resident)
  bf16x8 xf0[16], xf1[16];
  {
    const unsigned short* Xr0 = X + (size_t)(i0 + w * 64 + lc) * D_K + lh * 8;
#pragma unroll
    for (int kk = 0; kk < 16; ++kk) {
      xf0[kk] = *(const bf16x8*)(Xr0 + kk * 16);
      xf1[kk] = *(const bf16x8*)(Xr0 + 32 * D_K + kk * 16);
    }
  }

  float m0 = -INFINITY, s0 = 0.f, m1 = -INFINITY, s1 = 0.f;
  f32x16 accA0 = {}, accA1 = {}, accB0 = {}, accB1 = {};

  // Running per-lane swizzled source pointers (advance 1 tile per STAGE).
  const unsigned short* srcs[4];
  unsigned dsts[4];
#pragma unroll
  for (int r = 0; r < 4; ++r) {
    const int row = w * 8 + 2 * r + lh;
    srcs[r] = Y + (size_t)(j0 + row) * D_K + ((lc ^ (row & 7)) << 3);
    dsts[r] = w * 4096 + r * 1024;
  }

#define STAGE(bufidx)                                  \
  {                                                    \
    _Pragma("unroll") for (int r = 0; r < 4; ++r) {    \
      load_lds16(srcs[r], &lds[bufidx][dsts[r]]);      \
      srcs[r] += TJ * D_K;                             \
    }                                                  \
  }

  // ds_read address: lc*512 + (((2kk+lh)^(lc&7))<<4) == vb ^ (kk<<5)
  const unsigned vb = (unsigned)lc * 512 + ((unsigned)(lh ^ (lc & 7)) << 4);

  // Half-burst: 8 kk-steps x 2 subs = 16 MFMA from lds[bufidx]
#define HALF(bufidx, c0, c1, kklo)                                              \
  {                                                                            \
    const unsigned char* lb = &lds[bufidx][0];                                 \
    _Pragma("unroll") for (int kk = (kklo); kk < (kklo) + 8; ++kk) {           \
      bf16x8 y = *(const bf16x8*)(lb + (vb ^ (unsigned)(kk << 5)));            \
      c0 = __builtin_amdgcn_mfma_f32_32x32x16_bf16(y, xf0[kk], c0, 0, 0, 0);   \
      c1 = __builtin_amdgcn_mfma_f32_32x32x16_bf16(y, xf1[kk], c1, 0, 0, 0);   \
    }                                                                          \
  }

  // Pipelined consume: MFMA tile->cur interleaved with softmax of prev tile.
#define CPIPE(bufidx, c0, c1, p0, p1) \
  HALF(bufidx, c0, c1, 0);            \
  upd(m0, s0, p0);                    \
  HALF(bufidx, c0, c1, 8);            \
  upd(m1, s1, p1);

  // prologue: tile0 -> accA (no upd yet)
  STAGE(0);
  __syncthreads();                   // tile0 in buf0
  STAGE(1);                          // prefetch tile1
  HALF(0, accA0, accA1, 0);
  HALF(0, accA0, accA1, 8);
  __syncthreads();                   // tile1 in buf1; buf0 free

  // tiles 1..62 in pairs; tile t odd in buf1, even in buf0
  for (int t = 1; t < NT - 1; t += 2) {
    STAGE(0);                        // tile t+1 -> buf0 (t+1 <= 62)
    CPIPE(1, accB0, accB1, accA0, accA1);
    __syncthreads();                 // tile t+1 ready; buf1 free
    STAGE(1);                        // tile t+2 -> buf1 (t+2 <= 63)
    CPIPE(0, accA0, accA1, accB0, accB1);
    __syncthreads();                 // tile t+2 ready; buf0 free
  }
  // tile 63 (odd, buf1): fill accB, retire accA
  CPIPE(1, accB0, accB1, accA0, accA1);
  // retire accB
  upd(m0, s0, accB0);
  upd(m1, s1, accB1);
#undef STAGE
#undef HALF
#undef CPIPE

  // combine lane l with l^32 (same i, disjoint j_local subsets)
  {
    float mo = __shfl_xor(m0, 32), so = __shfl_xor(s0, 32);
    float mn = fmaxf(m0, mo);
    s0 = s0 * fexp2(m0 - mn) + so * fexp2(mo - mn); m0 = mn;
    mo = __shfl_xor(m1, 32); so = __shfl_xor(s1, 32);
    mn = fmaxf(m1, mo);
    s1 = s1 * fexp2(m1 - mn) + so * fexp2(mo - mn); m1 = mn;
  }

  // per-wave rows complete over this block's j-range: write partials
  if (lh == 0) {
    const int base = js * (2 * B_N) + dir * B_N + i0 + w * 64 + lc;
    pm[base] = m0;      ps[base] = s0;
    pm[base + 32] = m1; ps[base + 32] = s1;
  }
}

// ---------------------------------------------------------------------------
// 3) combine JS partials per (dir,i) -> lse (natural log)
// ---------------------------------------------------------------------------
__global__ void combine_kernel(const float* __restrict__ pm, const float* __restrict__ ps,
                               float* __restrict__ lse) {
  int id = blockIdx.x * 256 + threadIdx.x;  // dir*B_N + i
  float m = -INFINITY, s = 0.f;
#pragma unroll
  for (int p = 0; p < JS; ++p) {
    float mo = pm[p * (2 * B_N) + id], so = ps[p * (2 * B_N) + id];
    float mn = fmaxf(m, mo);
    s = s * fexp2(m - mn) + so * fexp2(mo - mn);
    m = mn;
  }
  lse[id] = 0.6931471805599453f * (m + log2f(s));
}

// ---------------------------------------------------------------------------
// 4) final: loss = mean( 0.5*(lse_r+lse_c) - scale*diag )
// ---------------------------------------------------------------------------
__global__ void final_kernel(const float* __restrict__ lse, const float* __restrict__ diag,
                             const float* __restrict__ lsp, float* __restrict__ out) {
  const float scale = fminf(expf(lsp[0]), 100.0f);
  float part = 0.f;
  for (int i = threadIdx.x; i < B_N; i += 1024)
    part += 0.5f * (lse[i] + lse[B_N + i]) - scale * diag[i];
  __shared__ float red[1024];
  red[threadIdx.x] = part;
  __syncthreads();
  for (int off = 512; off; off >>= 1) {
    if (threadIdx.x < off) red[threadIdx.x] += red[threadIdx.x + off];
    __syncthreads();
  }
  if (threadIdx.x == 0) {
    float loss = red[0] / (float)B_N;
    out[0] = loss;
    out[1] = loss;
  }
}

extern "C" void kernel_launch(void* const* d_in, const int* in_sizes, int n_in,
                              void* d_out, int out_size, void* d_ws, size_t ws_size,
                              hipStream_t stream) {
  const float* A  = (const float*)d_in[0];  // z_schema
  const float* Bm = (const float*)d_in[1];  // z_seal
  const float* ls = (const float*)d_in[2];  // logit_scale
  float* out = (float*)d_out;

  char* ws = (char*)d_ws;
  unsigned short* Abf = (unsigned short*)ws;                        // 8 MB
  unsigned short* Bbf = Abf + (size_t)B_N * D_K;                    // 8 MB
  float* diagp = (float*)(ws + 2ull * B_N * D_K * 2);               // 64 KB
  float* lsep  = diagp + B_N;                                       // 128 KB
  float* pm    = lsep + 2 * B_N;                                    // 1 MB
  float* ps    = pm + JS * 2 * B_N;                                 // 1 MB

  convert_diag_kernel<<<4096, 256, 0, stream>>>(A, Bm, ls, Abf, Bbf, diagp);
  lse_kernel<<<1024, 256, 0, stream>>>(Abf, Bbf, pm, ps);
  combine_kernel<<<128, 256, 0, stream>>>(pm, ps, lsep);
  final_kernel<<<1, 1024, 0, stream>>>(lsep, diagp, ls, out);
}

// Round 9
// 320.011 us; speedup vs baseline: 1.3768x; 1.2062x over previous
//
#include <hip/hip_runtime.h>
#include <hip/hip_bf16.h>
#include <math.h>

#define B_N 16384
#define D_K 256
#define JS 8
#define JRANGE (B_N / JS)          // 2048 j-rows per block
#define TJ 64                      // j-rows per LDS tile (R9: was 32)
#define NT (JRANGE / TJ)           // 32 tiles
#define TILE_BYTES (TJ * D_K * 2)  // 32 KB

typedef __bf16 bf16x8 __attribute__((ext_vector_type(8)));
typedef float f32x16 __attribute__((ext_vector_type(16)));

__device__ __forceinline__ unsigned short f2bf(float x) {
  unsigned u = __float_as_uint(x);
  unsigned r = (u + 0x7fffu + ((u >> 16) & 1u)) >> 16;
  return (unsigned short)r;
}

__device__ __forceinline__ float fexp2(float x) {
#if __has_builtin(__builtin_amdgcn_exp2f)
  return __builtin_amdgcn_exp2f(x);
#else
  return exp2f(x);
#endif
}

__device__ __forceinline__ void load_lds16(const void* g, void* l) {
  __builtin_amdgcn_global_load_lds(
      (const __attribute__((address_space(1))) unsigned int*)g,
      (__attribute__((address_space(3))) unsigned int*)l, 16, 0, 0);
}

// ---------------------------------------------------------------------------
// 1) fp32 -> bf16 (z_seal pre-scaled by scale*log2e) + diag (exact fp32).
// ---------------------------------------------------------------------------
__global__ void convert_diag_kernel(const float* __restrict__ A, const float* __restrict__ Bm,
                                    const float* __restrict__ lsp,
                                    unsigned short* __restrict__ Abf,
                                    unsigned short* __restrict__ Bbf,
                                    float* __restrict__ diag) {
  const float c = fminf(expf(lsp[0]), 100.0f) * 1.4426950408889634f;
  const int tid = threadIdx.x;
  const int idx = (blockIdx.x * 256 + tid) * 4;
  float4 a = *(const float4*)(A + idx);
  float4 b = *(const float4*)(Bm + idx);
  ushort4 ua, ub;
  ua.x = f2bf(a.x); ua.y = f2bf(a.y); ua.z = f2bf(a.z); ua.w = f2bf(a.w);
  ub.x = f2bf(b.x * c); ub.y = f2bf(b.y * c); ub.z = f2bf(b.z * c); ub.w = f2bf(b.w * c);
  *(ushort4*)(Abf + idx) = ua;
  *(ushort4*)(Bbf + idx) = ub;
  float d = a.x * b.x + a.y * b.y + a.z * b.z + a.w * b.w;
#pragma unroll
  for (int off = 32; off; off >>= 1) d += __shfl_xor(d, off);
  if ((tid & 63) == 0) diag[blockIdx.x * 4 + (tid >> 6)] = d;
}

// ---------------------------------------------------------------------------
// 2) Fused GEMM + online logsumexp. R5 skeleton (64 i-rows/wave, xf
//    reg-resident, 2 waves/SIMD) + TJ=64 (half the barriers/ptr-arith per j)
//    + immediate-folded ds_read addresses (zero addr VALU in the loop).
//    R4/R7/R8 lessons: xf MUST be reg-resident; total regs must land in
//    (128,256] (2 waves/SIMD). Tripwire: FETCH_SIZE ~75MB, WRITE ~2MB.
// ---------------------------------------------------------------------------
__device__ __forceinline__ void upd(float& m, float& s, const f32x16& a) {
  float x0 = fmaxf(fmaxf(a[0], a[1]), a[2]);
  float x1 = fmaxf(fmaxf(a[3], a[4]), a[5]);
  float x2 = fmaxf(fmaxf(a[6], a[7]), a[8]);
  float x3 = fmaxf(fmaxf(a[9], a[10]), a[11]);
  float x4 = fmaxf(fmaxf(a[12], a[13]), a[14]);
  float y0 = fmaxf(fmaxf(x0, x1), x2);
  float y1 = fmaxf(fmaxf(x3, x4), a[15]);
  float mn = fmaxf(m, fmaxf(y0, y1));
  s *= fexp2(m - mn);
  float p0 = fexp2(a[0] - mn), p1 = fexp2(a[1] - mn);
  float p2 = fexp2(a[2] - mn), p3 = fexp2(a[3] - mn);
  p0 += fexp2(a[4] - mn);  p1 += fexp2(a[5] - mn);
  p2 += fexp2(a[6] - mn);  p3 += fexp2(a[7] - mn);
  p0 += fexp2(a[8] - mn);  p1 += fexp2(a[9] - mn);
  p2 += fexp2(a[10] - mn); p3 += fexp2(a[11] - mn);
  p0 += fexp2(a[12] - mn); p1 += fexp2(a[13] - mn);
  p2 += fexp2(a[14] - mn); p3 += fexp2(a[15] - mn);
  s += (p0 + p1) + (p2 + p3);
  m = mn;
}

__global__ __launch_bounds__(256, 2) void lse_kernel(const unsigned short* __restrict__ Abf,
                                                     const unsigned short* __restrict__ Bbf,
                                                     float* __restrict__ pm,
                                                     float* __restrict__ ps) {
  __shared__ __align__(16) unsigned char lds[2][TILE_BYTES];
  const int bid = blockIdx.x;
  const int dir = bid >> 9;            // 0/1
  const int iblk = (bid >> 3) & 63;    // 64 i-blocks of 256 rows
  const int js = bid & 7;              // low bits -> same js pinned per XCD
  const unsigned short* X = dir ? Bbf : Abf;
  const unsigned short* Y = dir ? Abf : Bbf;
  const int i0 = iblk * 256;
  const int j0 = js * JRANGE;
  const int w = threadIdx.x >> 6;
  const int l = threadIdx.x & 63;
  const int lc = l & 31, lh = l >> 5;

  // X fragments: this wave's 64 rows x 256 k (128 VGPR, register-resident)
  bf16x8 xf0[16], xf1[16];
  {
    const unsigned short* Xr0 = X + (size_t)(i0 + w * 64 + lc) * D_K + lh * 8;
#pragma unroll
    for (int kk = 0; kk < 16; ++kk) {
      xf0[kk] = *(const bf16x8*)(Xr0 + kk * 16);
      xf1[kk] = *(const bf16x8*)(Xr0 + 32 * D_K + kk * 16);
    }
  }

  float m0 = -INFINITY, s0 = 0.f, m1 = -INFINITY, s1 = 0.f;

  // STAGE: 8 rounds of global_load_lds; wave w fills rows [w*16, w*16+16).
  // Round r covers rows w*16+2r+lh (lane halves); content pre-swizzled so
  // LDS slot lc holds global granule lc ^ (row&7)  (rule #21 pair).
  const unsigned short* srcs[8];
#pragma unroll
  for (int r = 0; r < 8; ++r) {
    const int row = w * 16 + 2 * r + lh;
    srcs[r] = Y + (size_t)(j0 + row) * D_K + ((lc ^ (row & 7)) << 3);
  }

#define STAGE(bufidx)                                           \
  {                                                             \
    _Pragma("unroll") for (int r = 0; r < 8; ++r) {             \
      load_lds16(srcs[r], &lds[bufidx][w * 8192 + r * 1024]);   \
      srcs[r] += TJ * D_K;                                      \
    }                                                           \
  }

  // ds_read addressing: row (jh*32+lc), slot (2kk+lh)^(lc&7):
  //   addr = [vb ^ ((kk&3)<<5)] + (kk>>2)*128 + jh*16384 + buf*32768
  // 4 base regs + compile-time immediates (max 65520 < 2^16)  -> zero
  // per-read VALU; compiler emits ds_read_b128 ... offset:N.
  const unsigned vb = (unsigned)lc * 512 + ((unsigned)(lh ^ (lc & 7)) << 4);
  const unsigned char* lb = &lds[0][0];
  const unsigned char* bq0 = lb + (vb ^ 0u);
  const unsigned char* bq1 = lb + (vb ^ 32u);
  const unsigned char* bq2 = lb + (vb ^ 64u);
  const unsigned char* bq3 = lb + (vb ^ 96u);

#define CONSUME(bufidx, jh)                                                     \
  {                                                                            \
    f32x16 acc0 = {};                                                          \
    f32x16 acc1 = {};                                                          \
    __builtin_amdgcn_s_setprio(1);                                             \
    _Pragma("unroll") for (int kk = 0; kk < 16; ++kk) {                        \
      const unsigned char* bp = ((kk & 3) == 0) ? bq0                          \
                              : ((kk & 3) == 1) ? bq1                          \
                              : ((kk & 3) == 2) ? bq2 : bq3;                   \
      bf16x8 y = *(const bf16x8*)(bp + (kk >> 2) * 128 + (jh)*16384 +          \
                                  (bufidx)*32768);                             \
      acc0 = __builtin_amdgcn_mfma_f32_32x32x16_bf16(y, xf0[kk], acc0, 0, 0, 0);\
      acc1 = __builtin_amdgcn_mfma_f32_32x32x16_bf16(y, xf1[kk], acc1, 0, 0, 0);\
    }                                                                          \
    __builtin_amdgcn_s_setprio(0);                                             \
    upd(m0, s0, acc0);                                                         \
    upd(m1, s1, acc1);                                                         \
  }

  STAGE(0);
  for (int t = 0; t < NT; t += 2) {
    __syncthreads();                   // buf0 (tile t) ready for all waves
    if (t + 1 < NT) STAGE(1);          // prefetch tile t+1
    CONSUME(0, 0);
    CONSUME(0, 1);
    __syncthreads();                   // buf1 ready; all done reading buf0
    if (t + 2 < NT) STAGE(0);          // prefetch tile t+2
    CONSUME(1, 0);
    CONSUME(1, 1);
  }
#undef STAGE
#undef CONSUME

  // combine lane l with l^32 (same i, disjoint j_local subsets)
  {
    float mo = __shfl_xor(m0, 32), so = __shfl_xor(s0, 32);
    float mn = fmaxf(m0, mo);
    s0 = s0 * fexp2(m0 - mn) + so * fexp2(mo - mn); m0 = mn;
    mo = __shfl_xor(m1, 32); so = __shfl_xor(s1, 32);
    mn = fmaxf(m1, mo);
    s1 = s1 * fexp2(m1 - mn) + so * fexp2(mo - mn); m1 = mn;
  }

  // per-wave rows complete over this block's j-range: write partials
  if (lh == 0) {
    const int base = js * (2 * B_N) + dir * B_N + i0 + w * 64 + lc;
    pm[base] = m0;      ps[base] = s0;
    pm[base + 32] = m1; ps[base + 32] = s1;
  }
}

// ---------------------------------------------------------------------------
// 3) combine JS partials per (dir,i) -> lse; fold diag; block-reduce;
//    one atomicAdd per block into acc[0].
// ---------------------------------------------------------------------------
__global__ void combine_kernel(const float* __restrict__ pm, const float* __restrict__ ps,
                               const float* __restrict__ diag, const float* __restrict__ lsp,
                               float* __restrict__ acc) {
  const int id = blockIdx.x * 256 + threadIdx.x;  // dir*B_N + i
  float m = -INFINITY, s = 0.f;
#pragma unroll
  for (int p = 0; p < JS; ++p) {
    float mo = pm[p * (2 * B_N) + id], so = ps[p * (2 * B_N) + id];
    float mn = fmaxf(m, mo);
    s = s * fexp2(m - mn) + so * fexp2(mo - mn);
    m = mn;
  }
  float v = 0.5f * 0.6931471805599453f * (m + log2f(s));
  if (id < B_N) {
    const float scale = fminf(expf(lsp[0]), 100.0f);
    v -= scale * diag[id];
  }
  __shared__ float red[256];
  red[threadIdx.x] = v;
  __syncthreads();
#pragma unroll
  for (int off = 128; off; off >>= 1) {
    if (threadIdx.x < off) red[threadIdx.x] += red[threadIdx.x + off];
    __syncthreads();
  }
  if (threadIdx.x == 0) atomicAdd(acc, red[0]);
}

// ---------------------------------------------------------------------------
// 4) final: loss = acc / B  (both outputs)
// ---------------------------------------------------------------------------
__global__ void final_kernel(const float* __restrict__ acc, float* __restrict__ out) {
  float loss = acc[0] / (float)B_N;
  out[0] = loss;
  out[1] = loss;
}

extern "C" void kernel_launch(void* const* d_in, const int* in_sizes, int n_in,
                              void* d_out, int out_size, void* d_ws, size_t ws_size,
                              hipStream_t stream) {
  const float* A  = (const float*)d_in[0];  // z_schema
  const float* Bm = (const float*)d_in[1];  // z_seal
  const float* ls = (const float*)d_in[2];  // logit_scale
  float* out = (float*)d_out;

  char* ws = (char*)d_ws;
  unsigned short* Abf = (unsigned short*)ws;                        // 8 MB
  unsigned short* Bbf = Abf + (size_t)B_N * D_K;                    // 8 MB
  float* diagp = (float*)(ws + 2ull * B_N * D_K * 2);               // 64 KB
  float* pm    = diagp + B_N;                                       // 1 MB
  float* ps    = pm + JS * 2 * B_N;                                 // 1 MB
  float* accp  = ps + JS * 2 * B_N;                                 // 4 B

  hipMemsetAsync(accp, 0, sizeof(float), stream);
  convert_diag_kernel<<<4096, 256, 0, stream>>>(A, Bm, ls, Abf, Bbf, diagp);
  lse_kernel<<<1024, 256, 0, stream>>>(Abf, Bbf, pm, ps);
  combine_kernel<<<128, 256, 0, stream>>>(pm, ps, diagp, ls, accp);
  final_kernel<<<1, 1, 0, stream>>>(accp, out);
}